// Round 1
// baseline (143.510 us; speedup 1.0000x reference)
//
#include <hip/hip_runtime.h>
#include <stdint.h>

// Sizes (fixed by the problem):
//   h: (8,1024,512) f32, s: (8,128,1024) f32 -> flat (1024,1024)
//   Wh: (512,128), Ws: (1024,128), b,v: (128,)
//   out: (8,128,1024) f32 softmax rows
//
// Workspace layout (needs ~15 MB):
//   phT : 8 * 128 * 1024 f32   (4 MB)   phT[n][a][x] = (h@Wh)[n,x,a]
//   psT : 128 * 1024 f32       (512 KB) psT[a][n*128+y] = (s@Ws+b)[n,y,a]
//   hb  : 8192*512  bf16       (8 MB)
//   sb  : 1024*1024 bf16       (2 MB)
//   WhT : 128*512   bf16       (128 KB)
//   WsT : 128*1024  bf16       (256 KB)

typedef float  f32x4  __attribute__((ext_vector_type(4)));
typedef __bf16 bf16x8 __attribute__((ext_vector_type(8)));
typedef __bf16 bf16x4 __attribute__((ext_vector_type(4)));

#define LOG2E      1.4426950408889634f
#define TWO_LOG2E  2.8853900817779268f

__device__ __forceinline__ float fast_tanh(float x) {
    // tanh(x) = 1 - 2/(exp(2x)+1); exp(2x)=exp2(x*2*log2e)
    float z = __builtin_amdgcn_exp2f(x * TWO_LOG2E);
    float r = __builtin_amdgcn_rcpf(z + 1.0f);
    return fmaf(-2.0f, r, 1.0f);
}

// ---------------------------------------------------------------- cast kernel
__global__ void __launch_bounds__(256) cast_fp32_bf16(
    const float4* __restrict__ h, const float4* __restrict__ s,
    bf16x4* __restrict__ hb, bf16x4* __restrict__ sb)
{
    const int NH = (8192 * 512) / 4;   // 1048576 float4s
    const int NS = (1024 * 1024) / 4;  // 262144 float4s
    int stride = gridDim.x * blockDim.x;
    for (int i = blockIdx.x * blockDim.x + threadIdx.x; i < NH + NS; i += stride) {
        float4 v = (i < NH) ? h[i] : s[i - NH];
        bf16x4 o;
        o.x = (__bf16)v.x; o.y = (__bf16)v.y; o.z = (__bf16)v.z; o.w = (__bf16)v.w;
        if (i < NH) hb[i] = o; else sb[i - NH] = o;
    }
}

// ------------------------------------------------- weight transpose + cast
// WhT[a][c] = Wh[c][a] (bf16), WsT[a][d] = Ws[d][a] (bf16)
__global__ void __launch_bounds__(256) transpose_cast(
    const float* __restrict__ Wh, const float* __restrict__ Ws,
    __bf16* __restrict__ WhT, __bf16* __restrict__ WsT)
{
    int bid = blockIdx.x;  // 0..7 -> Wh tiles, 8..23 -> Ws tiles
    const float* src; __bf16* dst; int K, c0;
    if (bid < 8) { src = Wh; dst = WhT; K = 512;  c0 = bid * 64; }
    else         { src = Ws; dst = WsT; K = 1024; c0 = (bid - 8) * 64; }
    __shared__ float tile[64][129];  // +1 pad breaks bank conflicts on transposed read
    int t = threadIdx.x;
    for (int i = 0; i < 8192; i += 256) {
        int idx = i + t;
        int r = idx >> 7, col = idx & 127;              // 64 rows(c) x 128 cols(a)
        tile[r][col] = src[(size_t)(c0 + r) * 128 + col];
    }
    __syncthreads();
    for (int i = 0; i < 8192; i += 256) {
        int idx = i + t;
        int a = idx >> 6, cc = idx & 63;                // write 128 rows(a) x 64 cols(c)
        dst[(size_t)a * K + c0 + cc] = (__bf16)tile[cc][a];
    }
}

// ------------------------------------------------------------- MFMA GEMM (NT)
// C[m][n] = sum_k A[m][k]*B[n][k]  (both k-contiguous), C stored row-major ldc=1024.
// blocks 0..127  : phT  (A=WhT 128x512,  B=h rows,  per (n, xtile of 64))
// blocks 128..143: psT  (A=WsT 128x1024, B=s rows,  per (ny tile of 64), +bias)
__global__ void __launch_bounds__(256) gemm_nt(
    const __bf16* __restrict__ WhT, const __bf16* __restrict__ WsT,
    const __bf16* __restrict__ hb,  const __bf16* __restrict__ sb,
    float* __restrict__ phT, float* __restrict__ psT, const float* __restrict__ bias)
{
    int bid = blockIdx.x;
    const __bf16 *A, *B; float* C; const float* bptr = nullptr; int K;
    if (bid < 128) {
        int n = bid >> 4, xt = bid & 15;
        A = WhT; K = 512;
        B = hb + (size_t)(n * 1024 + xt * 64) * 512;
        C = phT + (size_t)n * 128 * 1024 + xt * 64;
    } else {
        int tt = bid - 128;
        A = WsT; K = 1024;
        B = sb + (size_t)tt * 64 * 1024;
        C = psT + tt * 64;
        bptr = bias;
    }
    __shared__ __bf16 As[128 * 32] __attribute__((aligned(16)));  // [row a][k]
    __shared__ __bf16 Bs[64 * 32]  __attribute__((aligned(16)));  // [row x][k]
    int tid = threadIdx.x, lane = tid & 63, w = tid >> 6;

    f32x4 acc[8] = {};  // 8 m-tiles of 16, wave w owns n-cols [w*16, w*16+16)

    for (int k0 = 0; k0 < K; k0 += 32) {
        __syncthreads();
        // stage A: 512 chunks of 16B, 2 per thread. chunk j -> row j>>2, k-off (j&3)*8
        {
            int j = tid;
            *(bf16x8*)&As[j * 8] =
                *(const bf16x8*)(A + (size_t)(j >> 2) * K + k0 + (j & 3) * 8);
            j = tid + 256;
            *(bf16x8*)&As[j * 8] =
                *(const bf16x8*)(A + (size_t)(j >> 2) * K + k0 + (j & 3) * 8);
        }
        // stage B: 256 chunks of 16B, 1 per thread
        {
            int j = tid;
            *(bf16x8*)&Bs[j * 8] =
                *(const bf16x8*)(B + (size_t)(j >> 2) * K + k0 + (j & 3) * 8);
        }
        __syncthreads();
        // B fragment: lane holds B[k=quad*8+j][n=lane&15] -> Bs row w*16+(lane&15)
        bf16x8 bfrag = *(const bf16x8*)&Bs[(w * 16 + (lane & 15)) * 32 + (lane >> 4) * 8];
        #pragma unroll
        for (int i = 0; i < 8; ++i) {
            bf16x8 afrag =
                *(const bf16x8*)&As[(i * 16 + (lane & 15)) * 32 + (lane >> 4) * 8];
            acc[i] = __builtin_amdgcn_mfma_f32_16x16x32_bf16(afrag, bfrag, acc[i], 0, 0, 0);
        }
    }
    // epilogue: C/D layout col=lane&15, row=quad*4+reg  (m89-verified)
    int colBase = w * 16 + (lane & 15);
    int rowBase = (lane >> 4) * 4;
    #pragma unroll
    for (int i = 0; i < 8; ++i) {
        #pragma unroll
        for (int r = 0; r < 4; ++r) {
            int m = i * 16 + rowBase + r;
            float vv = acc[i][r];
            if (bptr) vv += bptr[m];
            C[(size_t)m * 1024 + colBase] = vv;
        }
    }
}

// ------------------------------------------- fused tanh-dot + softmax kernel
// block = (n, ygroup of 4), 512 threads; thread t owns x = {2t, 2t+1}
__global__ void __launch_bounds__(512) attn_softmax(
    const float* __restrict__ phT, const float* __restrict__ psT,
    const float* __restrict__ v, float* __restrict__ out)
{
    int bid = blockIdx.x;            // 256 blocks
    int n = bid >> 5, yg = bid & 31;
    int nyBase = n * 128 + yg * 4;   // 4 consecutive global rows
    const float2* phv = (const float2*)(phT + (size_t)n * 128 * 1024);
    int t = threadIdx.x;

    __shared__ float ps_s[4 * 128];
    __shared__ float v_s[128];
    __shared__ float wred[4][8];

    {   // stage ps rows (4 x 128) from psT (transposed)
        int a = t >> 2, y = t & 3;
        ps_s[y * 128 + a] = psT[(size_t)a * 1024 + nyBase + y];
    }
    if (t < 128) v_s[t] = v[t];
    __syncthreads();

    float acc0[4] = {0, 0, 0, 0}, acc1[4] = {0, 0, 0, 0};
    #pragma unroll 4
    for (int a = 0; a < 128; ++a) {
        float2 p2 = phv[a * 512 + t];     // coalesced: lane = x/2
        float sv = v_s[a];
        #pragma unroll
        for (int y = 0; y < 4; ++y) {
            float ps = ps_s[y * 128 + a];
            acc0[y] = fmaf(sv, fast_tanh(ps + p2.x), acc0[y]);
            acc1[y] = fmaf(sv, fast_tanh(ps + p2.y), acc1[y]);
        }
    }

    int lane = t & 63, wv = t >> 6;
    // block-wide max per y
    #pragma unroll
    for (int y = 0; y < 4; ++y) {
        float mx = fmaxf(acc0[y], acc1[y]);
        for (int m = 32; m; m >>= 1) mx = fmaxf(mx, __shfl_xor(mx, m));
        if (lane == 0) wred[y][wv] = mx;
    }
    __syncthreads();
    float mxv[4];
    #pragma unroll
    for (int y = 0; y < 4; ++y) {
        float mx = wred[y][0];
        #pragma unroll
        for (int i = 1; i < 8; ++i) mx = fmaxf(mx, wred[y][i]);
        mxv[y] = mx;
    }
    __syncthreads();
    // exp + block-wide sum per y
    float e0[4], e1[4];
    #pragma unroll
    for (int y = 0; y < 4; ++y) {
        e0[y] = __builtin_amdgcn_exp2f((acc0[y] - mxv[y]) * LOG2E);
        e1[y] = __builtin_amdgcn_exp2f((acc1[y] - mxv[y]) * LOG2E);
        float sm = e0[y] + e1[y];
        for (int m = 32; m; m >>= 1) sm += __shfl_xor(sm, m);
        if (lane == 0) wred[y][wv] = sm;
    }
    __syncthreads();
    #pragma unroll
    for (int y = 0; y < 4; ++y) {
        float sm = 0.f;
        #pragma unroll
        for (int i = 0; i < 8; ++i) sm += wred[y][i];
        float r = __builtin_amdgcn_rcpf(sm);
        float2 o; o.x = e0[y] * r; o.y = e1[y] * r;
        ((float2*)(out + (size_t)(nyBase + y) * 1024))[t] = o;
    }
}

// ----------------------------------------------------------------- launcher
extern "C" void kernel_launch(void* const* d_in, const int* in_sizes, int n_in,
                              void* d_out, int out_size, void* d_ws, size_t ws_size,
                              hipStream_t stream) {
    const float* h  = (const float*)d_in[0];
    const float* s  = (const float*)d_in[1];
    const float* Wh = (const float*)d_in[2];
    const float* Ws = (const float*)d_in[3];
    const float* b  = (const float*)d_in[4];
    const float* v  = (const float*)d_in[5];
    float* out = (float*)d_out;

    char* ws = (char*)d_ws;
    float*  phT = (float*)ws;                                   // 4 MB
    float*  psT = (float*)(ws + (4u << 20));                    // 512 KB
    __bf16* hb  = (__bf16*)(ws + (4u << 20) + (512u << 10));    // 8 MB
    __bf16* sb  = hb + (size_t)8192 * 512;                      // 2 MB
    __bf16* WhT = sb + (size_t)1024 * 1024;                     // 128 KB
    __bf16* WsT = WhT + (size_t)128 * 512;                      // 256 KB

    cast_fp32_bf16<<<1024, 256, 0, stream>>>(
        (const float4*)h, (const float4*)s, (bf16x4*)hb, (bf16x4*)sb);
    transpose_cast<<<24, 256, 0, stream>>>(Wh, Ws, WhT, WsT);
    gemm_nt<<<144, 256, 0, stream>>>(WhT, WsT, hb, sb, phT, psT, b);
    attn_softmax<<<256, 512, 0, stream>>>(phT, psT, v, out);
}

// Round 2
// 143.388 us; speedup vs baseline: 1.0009x; 1.0009x over previous
//
#include <hip/hip_runtime.h>
#include <stdint.h>

// Sizes: h (8,1024,512) f32, s (8,128,1024)->(1024,1024) f32,
//        Wh (512,128), Ws (1024,128), b,v (128,), out (8,128,1024) f32.
//
// Pipeline (3 kernels):
//   1. transpose_cast : WhT[a][c], WsT[a][d] bf16 (k-contiguous A operands)
//   2. gemm_fused     : barrier-free register MFMA GEMM, f32 activations
//                       cast to bf16 in-register; epilogue scales by 2*log2e
//                       (and adds bias for ps) -> phT[n][a][x], psT[a][ny]
//   3. attn_softmax   : e = v . tanh(ps+ph) via rcp(exp2(arg)+1), fused
//                       row softmax. 512 blocks x 512 thr.

typedef float  f32x4  __attribute__((ext_vector_type(4)));
typedef __bf16 bf16x8 __attribute__((ext_vector_type(8)));

#define LOG2E     1.4426950408889634f
#define TWO_LOG2E 2.8853900817779268f

// ------------------------------------------------- weight transpose + cast
__global__ void __launch_bounds__(256) transpose_cast(
    const float* __restrict__ Wh, const float* __restrict__ Ws,
    __bf16* __restrict__ WhT, __bf16* __restrict__ WsT)
{
    int bid = blockIdx.x;  // 0..7 -> Wh tiles, 8..23 -> Ws tiles
    const float* src; __bf16* dst; int K, c0;
    if (bid < 8) { src = Wh; dst = WhT; K = 512;  c0 = bid * 64; }
    else         { src = Ws; dst = WsT; K = 1024; c0 = (bid - 8) * 64; }
    __shared__ float tile[64][129];
    int t = threadIdx.x;
    for (int i = 0; i < 8192; i += 256) {
        int idx = i + t;
        int r = idx >> 7, col = idx & 127;              // 64 rows(c) x 128 cols(a)
        tile[r][col] = src[(size_t)(c0 + r) * 128 + col];
    }
    __syncthreads();
    for (int i = 0; i < 8192; i += 256) {
        int idx = i + t;
        int a = idx >> 6, cc = idx & 63;                // 128 rows(a) x 64 cols(c)
        dst[(size_t)a * K + c0 + cc] = (__bf16)tile[cc][a];
    }
}

// --------------------------------------- barrier-free register MFMA GEMM
// blocks 0..255 : phT  (A=WhT 128x512,  B=h f32,  32 cols/block)
// blocks 256..287: psT (A=WsT 128x1024, B=s f32,  32 cols/block, +bias)
// wave w: m-half = (w&1)*64 (4 m-tiles), col-group = (w>>1)*16.
__global__ void __launch_bounds__(256) gemm_fused(
    const __bf16* __restrict__ WhT, const __bf16* __restrict__ WsT,
    const float* __restrict__ h, const float* __restrict__ s,
    float* __restrict__ phT, float* __restrict__ psT,
    const float* __restrict__ bias)
{
    int bid = blockIdx.x;
    int tid = threadIdx.x, lane = tid & 63, w = tid >> 6;
    int mbase = (w & 1) * 64;
    const __bf16* A; const float* B; float* Cp; int K; bool isPs;
    int colg;
    if (bid < 256) {
        isPs = false; A = WhT; B = h; K = 512;
        colg = bid * 32 + (w >> 1) * 16;
        int n = colg >> 10, x = colg & 1023;
        Cp = phT + (size_t)n * 131072 + x;     // + m*1024 + col in epilogue
    } else {
        isPs = true; A = WsT; B = s; K = 1024;
        colg = (bid - 256) * 32 + (w >> 1) * 16;
        Cp = psT + colg;
    }
    int q = lane >> 4;
    const float*  Bp = B + (size_t)(colg + (lane & 15)) * K + q * 8;
    const __bf16* Ap = A + (size_t)(mbase + (lane & 15)) * K + q * 8;

    f32x4 acc[4] = {};
    // prime the 2-stage pipeline
    float4 b0 = *(const float4*)(Bp);
    float4 b1 = *(const float4*)(Bp + 4);
    bf16x8 a_[4];
    #pragma unroll
    for (int i = 0; i < 4; ++i) a_[i] = *(const bf16x8*)(Ap + (size_t)i * 16 * K);

    for (int k0 = 0; k0 < K; k0 += 32) {
        int kn = k0 + 32; if (kn > K - 32) kn = K - 32;   // clamped (dup last)
        float4 nb0 = *(const float4*)(Bp + kn);
        float4 nb1 = *(const float4*)(Bp + kn + 4);
        bf16x8 na[4];
        #pragma unroll
        for (int i = 0; i < 4; ++i)
            na[i] = *(const bf16x8*)(Ap + (size_t)i * 16 * K + kn);
        bf16x8 bf;
        bf[0] = (__bf16)b0.x; bf[1] = (__bf16)b0.y;
        bf[2] = (__bf16)b0.z; bf[3] = (__bf16)b0.w;
        bf[4] = (__bf16)b1.x; bf[5] = (__bf16)b1.y;
        bf[6] = (__bf16)b1.z; bf[7] = (__bf16)b1.w;
        #pragma unroll
        for (int i = 0; i < 4; ++i)
            acc[i] = __builtin_amdgcn_mfma_f32_16x16x32_bf16(a_[i], bf, acc[i], 0, 0, 0);
        b0 = nb0; b1 = nb1;
        #pragma unroll
        for (int i = 0; i < 4; ++i) a_[i] = na[i];
    }

    // C/D layout: col=lane&15, row(within 16-tile)=q*4+r  (m89-verified)
    int col = lane & 15;
    #pragma unroll
    for (int i = 0; i < 4; ++i) {
        #pragma unroll
        for (int r = 0; r < 4; ++r) {
            int m = mbase + i * 16 + q * 4 + r;
            float vv = acc[i][r];
            if (isPs) vv += bias[m];
            Cp[(size_t)m * 1024 + col] = vv * TWO_LOG2E;   // pre-scale for exp2
        }
    }
}

// ------------------------------------------- fused tanh-dot + softmax
// block = (n, y-pair), 512 threads; thread t owns x = {2t, 2t+1}
__global__ void __launch_bounds__(512) attn_softmax(
    const float* __restrict__ phT, const float* __restrict__ psT,
    const float* __restrict__ v, float* __restrict__ out)
{
    int bid = blockIdx.x;            // 512 blocks = n(8) x yg(64)
    int n = bid >> 6, yg = bid & 63;
    int ny = n * 128 + yg * 2;       // 2 consecutive global rows
    const float2* ph2 = (const float2*)(phT + (size_t)n * 131072);
    int t = threadIdx.x;

    __shared__ float4 pv_s[128];     // {ps'[y0][a], ps'[y1][a], v[a], 0}
    __shared__ float wred[2][8];
    __shared__ float VsumS;

    if (t < 128) {
        float2 p = *(const float2*)(psT + (size_t)t * 1024 + ny);
        float4 pk; pk.x = p.x; pk.y = p.y; pk.z = v[t]; pk.w = 0.f;
        pv_s[t] = pk;
    }
    if (t < 64) {
        float vv = v[t] + v[t + 64];
        for (int m = 32; m; m >>= 1) vv += __shfl_xor(vv, m);
        if (t == 0) VsumS = vv;
    }
    __syncthreads();
    float Vsum = VsumS;

    // acc = sum_a v_a * rcp(exp2(arg)+1);  e = Vsum - 2*acc  (tanh identity)
    float acc00 = 0.f, acc01 = 0.f, acc10 = 0.f, acc11 = 0.f;
    #pragma unroll 4
    for (int a = 0; a < 128; ++a) {
        float4 pq = pv_s[a];                 // broadcast ds_read_b128
        float2 p2 = ph2[a * 512 + t];        // coalesced float2
        float z00 = __builtin_amdgcn_exp2f(pq.x + p2.x);
        float z01 = __builtin_amdgcn_exp2f(pq.x + p2.y);
        float z10 = __builtin_amdgcn_exp2f(pq.y + p2.x);
        float z11 = __builtin_amdgcn_exp2f(pq.y + p2.y);
        acc00 = fmaf(pq.z, __builtin_amdgcn_rcpf(z00 + 1.f), acc00);
        acc01 = fmaf(pq.z, __builtin_amdgcn_rcpf(z01 + 1.f), acc01);
        acc10 = fmaf(pq.z, __builtin_amdgcn_rcpf(z10 + 1.f), acc10);
        acc11 = fmaf(pq.z, __builtin_amdgcn_rcpf(z11 + 1.f), acc11);
    }
    float e00 = fmaf(-2.f, acc00, Vsum);
    float e01 = fmaf(-2.f, acc01, Vsum);
    float e10 = fmaf(-2.f, acc10, Vsum);
    float e11 = fmaf(-2.f, acc11, Vsum);

    int lane = t & 63, wv = t >> 6;
    // block max per y
    float mx0 = fmaxf(e00, e01), mx1 = fmaxf(e10, e11);
    for (int m = 32; m; m >>= 1) {
        mx0 = fmaxf(mx0, __shfl_xor(mx0, m));
        mx1 = fmaxf(mx1, __shfl_xor(mx1, m));
    }
    if (lane == 0) { wred[0][wv] = mx0; wred[1][wv] = mx1; }
    __syncthreads();
    mx0 = wred[0][0]; mx1 = wred[1][0];
    #pragma unroll
    for (int i = 1; i < 8; ++i) {
        mx0 = fmaxf(mx0, wred[0][i]);
        mx1 = fmaxf(mx1, wred[1][i]);
    }
    __syncthreads();
    // exp + block sum per y
    float s00 = __builtin_amdgcn_exp2f((e00 - mx0) * LOG2E);
    float s01 = __builtin_amdgcn_exp2f((e01 - mx0) * LOG2E);
    float s10 = __builtin_amdgcn_exp2f((e10 - mx1) * LOG2E);
    float s11 = __builtin_amdgcn_exp2f((e11 - mx1) * LOG2E);
    float sm0 = s00 + s01, sm1 = s10 + s11;
    for (int m = 32; m; m >>= 1) {
        sm0 += __shfl_xor(sm0, m);
        sm1 += __shfl_xor(sm1, m);
    }
    if (lane == 0) { wred[0][wv] = sm0; wred[1][wv] = sm1; }
    __syncthreads();
    sm0 = 0.f; sm1 = 0.f;
    #pragma unroll
    for (int i = 0; i < 8; ++i) { sm0 += wred[0][i]; sm1 += wred[1][i]; }
    float r0 = __builtin_amdgcn_rcpf(sm0);
    float r1 = __builtin_amdgcn_rcpf(sm1);
    float2 o0; o0.x = s00 * r0; o0.y = s01 * r0;
    float2 o1; o1.x = s10 * r1; o1.y = s11 * r1;
    ((float2*)(out + (size_t)(ny + 0) * 1024))[t] = o0;
    ((float2*)(out + (size_t)(ny + 1) * 1024))[t] = o1;
}

// ----------------------------------------------------------------- launcher
extern "C" void kernel_launch(void* const* d_in, const int* in_sizes, int n_in,
                              void* d_out, int out_size, void* d_ws, size_t ws_size,
                              hipStream_t stream) {
    const float* h  = (const float*)d_in[0];
    const float* s  = (const float*)d_in[1];
    const float* Wh = (const float*)d_in[2];
    const float* Ws = (const float*)d_in[3];
    const float* b  = (const float*)d_in[4];
    const float* v  = (const float*)d_in[5];
    float* out = (float*)d_out;

    char* ws = (char*)d_ws;
    float*  phT = (float*)ws;                                  // 4 MB
    float*  psT = (float*)(ws + (4u << 20));                   // 512 KB
    __bf16* WhT = (__bf16*)(ws + (4u << 20) + (512u << 10));   // 128 KB
    __bf16* WsT = WhT + (size_t)128 * 512;                     // 256 KB

    transpose_cast<<<24, 256, 0, stream>>>(Wh, Ws, WhT, WsT);
    gemm_fused<<<288, 256, 0, stream>>>(WhT, WsT, h, s, phT, psT, b);
    attn_softmax<<<512, 512, 0, stream>>>(phT, psT, v, out);
}

// Round 3
// 132.023 us; speedup vs baseline: 1.0870x; 1.0861x over previous
//
#include <hip/hip_runtime.h>
#include <stdint.h>

// Sizes: h (8,1024,512) f32, s (8,128,1024)->(1024,1024) f32,
//        Wh (512,128), Ws (1024,128), b,v (128,), out (8,128,1024) f32.
//
// Key identity: tanh(ps+ph) = 1 - 2/(Eps*Eph + 1),
//   Eps = exp2(2*log2e*ps), Eph = exp2(2*log2e*ph)  (precomputed in GEMM
//   epilogue over 1.18M elems instead of 134M exp2 in the attn loop).
// Attn inner op per element: fma(Eps,Eph,1) -> rcp -> fma(v,.,acc)
//   = 1 transcendental + 2 VALU (was 2 trans + 3 VALU).
//
// Pipeline:
//   1. transpose_cast : WhT[a][c], WsT[a][d] bf16 (k-contiguous A operands)
//   2. gemm_fused     : barrier-free register MFMA GEMM; epilogue writes
//                       Eph[n][a][x], Eps[a][ny]
//   3. attn_softmax   : e = Vsum - 2*sum_a v_a*rcp(Eps*Eph+1), fused softmax

typedef float  f32x4  __attribute__((ext_vector_type(4)));
typedef __bf16 bf16x8 __attribute__((ext_vector_type(8)));

#define LOG2E     1.4426950408889634f
#define TWO_LOG2E 2.8853900817779268f

// ------------------------------------------------- weight transpose + cast
__global__ void __launch_bounds__(256) transpose_cast(
    const float* __restrict__ Wh, const float* __restrict__ Ws,
    __bf16* __restrict__ WhT, __bf16* __restrict__ WsT)
{
    int bid = blockIdx.x;  // 0..7 -> Wh tiles, 8..23 -> Ws tiles
    const float* src; __bf16* dst; int K, c0;
    if (bid < 8) { src = Wh; dst = WhT; K = 512;  c0 = bid * 64; }
    else         { src = Ws; dst = WsT; K = 1024; c0 = (bid - 8) * 64; }
    __shared__ float tile[64][129];
    int t = threadIdx.x;
    for (int i = 0; i < 8192; i += 256) {
        int idx = i + t;
        int r = idx >> 7, col = idx & 127;              // 64 rows(c) x 128 cols(a)
        tile[r][col] = src[(size_t)(c0 + r) * 128 + col];
    }
    __syncthreads();
    for (int i = 0; i < 8192; i += 256) {
        int idx = i + t;
        int a = idx >> 6, cc = idx & 63;                // 128 rows(a) x 64 cols(c)
        dst[(size_t)a * K + c0 + cc] = (__bf16)tile[cc][a];
    }
}

// --------------------------------------- barrier-free register MFMA GEMM
// blocks 0..255 : Eph  (A=WhT 128x512,  B=h f32,  32 cols/block)
// blocks 256..287: Eps (A=WsT 128x1024, B=s f32,  32 cols/block, +bias)
// wave w: m-half = (w&1)*64 (4 m-tiles), col-group = (w>>1)*16.
__global__ void __launch_bounds__(256) gemm_fused(
    const __bf16* __restrict__ WhT, const __bf16* __restrict__ WsT,
    const float* __restrict__ h, const float* __restrict__ s,
    float* __restrict__ Eph, float* __restrict__ Eps,
    const float* __restrict__ bias)
{
    int bid = blockIdx.x;
    int tid = threadIdx.x, lane = tid & 63, w = tid >> 6;
    int mbase = (w & 1) * 64;
    const __bf16* A; const float* B; float* Cp; int K; bool isPs;
    int colg;
    if (bid < 256) {
        isPs = false; A = WhT; B = h; K = 512;
        colg = bid * 32 + (w >> 1) * 16;
        int n = colg >> 10, x = colg & 1023;
        Cp = Eph + (size_t)n * 131072 + x;     // + m*1024 + col in epilogue
    } else {
        isPs = true; A = WsT; B = s; K = 1024;
        colg = (bid - 256) * 32 + (w >> 1) * 16;
        Cp = Eps + colg;
    }
    int q = lane >> 4;
    const float*  Bp = B + (size_t)(colg + (lane & 15)) * K + q * 8;
    const __bf16* Ap = A + (size_t)(mbase + (lane & 15)) * K + q * 8;

    f32x4 acc[4] = {};
    float4 b0 = *(const float4*)(Bp);
    float4 b1 = *(const float4*)(Bp + 4);
    bf16x8 a_[4];
    #pragma unroll
    for (int i = 0; i < 4; ++i) a_[i] = *(const bf16x8*)(Ap + (size_t)i * 16 * K);

    for (int k0 = 0; k0 < K; k0 += 32) {
        int kn = k0 + 32; if (kn > K - 32) kn = K - 32;   // clamped (dup last)
        float4 nb0 = *(const float4*)(Bp + kn);
        float4 nb1 = *(const float4*)(Bp + kn + 4);
        bf16x8 na[4];
        #pragma unroll
        for (int i = 0; i < 4; ++i)
            na[i] = *(const bf16x8*)(Ap + (size_t)i * 16 * K + kn);
        bf16x8 bf;
        bf[0] = (__bf16)b0.x; bf[1] = (__bf16)b0.y;
        bf[2] = (__bf16)b0.z; bf[3] = (__bf16)b0.w;
        bf[4] = (__bf16)b1.x; bf[5] = (__bf16)b1.y;
        bf[6] = (__bf16)b1.z; bf[7] = (__bf16)b1.w;
        #pragma unroll
        for (int i = 0; i < 4; ++i)
            acc[i] = __builtin_amdgcn_mfma_f32_16x16x32_bf16(a_[i], bf, acc[i], 0, 0, 0);
        b0 = nb0; b1 = nb1;
        #pragma unroll
        for (int i = 0; i < 4; ++i) a_[i] = na[i];
    }

    // C/D layout: col=lane&15, row(within 16-tile)=q*4+r  (m89-verified)
    int col = lane & 15;
    #pragma unroll
    for (int i = 0; i < 4; ++i) {
        #pragma unroll
        for (int r = 0; r < 4; ++r) {
            int m = mbase + i * 16 + q * 4 + r;
            float vv = acc[i][r];
            if (isPs) vv += bias[m];
            // store exp2(2*log2e * val) -- the factored exponential
            Cp[(size_t)m * 1024 + col] =
                __builtin_amdgcn_exp2f(vv * TWO_LOG2E);
        }
    }
}

// ------------------------------------------- fused tanh-dot + softmax
// block = (n, y-pair), 512 threads; thread t owns x = {2t, 2t+1}
// e = Vsum - 2 * sum_a v_a * rcp(fma(Eps, Eph, 1))
__global__ void __launch_bounds__(512, 4) attn_softmax(
    const float* __restrict__ Eph, const float* __restrict__ Eps,
    const float* __restrict__ v, float* __restrict__ out)
{
    int bid = blockIdx.x;            // 512 blocks = n(8) x yg(64)
    int n = bid >> 6, yg = bid & 63;
    int ny = n * 128 + yg * 2;       // 2 consecutive global rows
    const float2* ph2 = (const float2*)(Eph + (size_t)n * 131072);
    int t = threadIdx.x;

    __shared__ float4 pv_s[128];     // {Eps[y0][a], Eps[y1][a], v[a], 0}
    __shared__ float wred[2][8];
    __shared__ float VsumS;

    if (t < 128) {
        float2 p = *(const float2*)(Eps + (size_t)t * 1024 + ny);
        float4 pk; pk.x = p.x; pk.y = p.y; pk.z = v[t]; pk.w = 0.f;
        pv_s[t] = pk;
    }
    if (t < 64) {
        float vv = v[t] + v[t + 64];
        for (int m = 32; m; m >>= 1) vv += __shfl_xor(vv, m);
        if (t == 0) VsumS = vv;
    }
    __syncthreads();
    float Vsum = VsumS;

    float acc00 = 0.f, acc01 = 0.f, acc10 = 0.f, acc11 = 0.f;
    #pragma unroll 8
    for (int a = 0; a < 128; ++a) {
        float4 pq = pv_s[a];                 // broadcast ds_read_b128
        float2 p2 = ph2[a * 512 + t];        // coalesced float2
        float z00 = fmaf(pq.x, p2.x, 1.f);
        float z01 = fmaf(pq.x, p2.y, 1.f);
        float z10 = fmaf(pq.y, p2.x, 1.f);
        float z11 = fmaf(pq.y, p2.y, 1.f);
        acc00 = fmaf(pq.z, __builtin_amdgcn_rcpf(z00), acc00);
        acc01 = fmaf(pq.z, __builtin_amdgcn_rcpf(z01), acc01);
        acc10 = fmaf(pq.z, __builtin_amdgcn_rcpf(z10), acc10);
        acc11 = fmaf(pq.z, __builtin_amdgcn_rcpf(z11), acc11);
    }
    float e00 = fmaf(-2.f, acc00, Vsum);
    float e01 = fmaf(-2.f, acc01, Vsum);
    float e10 = fmaf(-2.f, acc10, Vsum);
    float e11 = fmaf(-2.f, acc11, Vsum);

    int lane = t & 63, wv = t >> 6;
    float mx0 = fmaxf(e00, e01), mx1 = fmaxf(e10, e11);
    for (int m = 32; m; m >>= 1) {
        mx0 = fmaxf(mx0, __shfl_xor(mx0, m));
        mx1 = fmaxf(mx1, __shfl_xor(mx1, m));
    }
    if (lane == 0) { wred[0][wv] = mx0; wred[1][wv] = mx1; }
    __syncthreads();
    mx0 = wred[0][0]; mx1 = wred[1][0];
    #pragma unroll
    for (int i = 1; i < 8; ++i) {
        mx0 = fmaxf(mx0, wred[0][i]);
        mx1 = fmaxf(mx1, wred[1][i]);
    }
    __syncthreads();
    float s00 = __builtin_amdgcn_exp2f((e00 - mx0) * LOG2E);
    float s01 = __builtin_amdgcn_exp2f((e01 - mx0) * LOG2E);
    float s10 = __builtin_amdgcn_exp2f((e10 - mx1) * LOG2E);
    float s11 = __builtin_amdgcn_exp2f((e11 - mx1) * LOG2E);
    float sm0 = s00 + s01, sm1 = s10 + s11;
    for (int m = 32; m; m >>= 1) {
        sm0 += __shfl_xor(sm0, m);
        sm1 += __shfl_xor(sm1, m);
    }
    if (lane == 0) { wred[0][wv] = sm0; wred[1][wv] = sm1; }
    __syncthreads();
    sm0 = 0.f; sm1 = 0.f;
    #pragma unroll
    for (int i = 0; i < 8; ++i) { sm0 += wred[0][i]; sm1 += wred[1][i]; }
    float r0 = __builtin_amdgcn_rcpf(sm0);
    float r1 = __builtin_amdgcn_rcpf(sm1);
    float2 o0; o0.x = s00 * r0; o0.y = s01 * r0;
    float2 o1; o1.x = s10 * r1; o1.y = s11 * r1;
    ((float2*)(out + (size_t)(ny + 0) * 1024))[t] = o0;
    ((float2*)(out + (size_t)(ny + 1) * 1024))[t] = o1;
}

// ----------------------------------------------------------------- launcher
extern "C" void kernel_launch(void* const* d_in, const int* in_sizes, int n_in,
                              void* d_out, int out_size, void* d_ws, size_t ws_size,
                              hipStream_t stream) {
    const float* h  = (const float*)d_in[0];
    const float* s  = (const float*)d_in[1];
    const float* Wh = (const float*)d_in[2];
    const float* Ws = (const float*)d_in[3];
    const float* b  = (const float*)d_in[4];
    const float* v  = (const float*)d_in[5];
    float* out = (float*)d_out;

    char* ws = (char*)d_ws;
    float*  Eph = (float*)ws;                                  // 4 MB
    float*  Eps = (float*)(ws + (4u << 20));                   // 512 KB
    __bf16* WhT = (__bf16*)(ws + (4u << 20) + (512u << 10));   // 128 KB
    __bf16* WsT = WhT + (size_t)128 * 512;                     // 256 KB

    transpose_cast<<<24, 256, 0, stream>>>(Wh, Ws, WhT, WsT);
    gemm_fused<<<288, 256, 0, stream>>>(WhT, WsT, h, s, Eph, Eps, b);
    attn_softmax<<<512, 512, 0, stream>>>(Eph, Eps, v, out);
}